// Round 1
// baseline (481.230 us; speedup 1.0000x reference)
//
#include <hip/hip_runtime.h>

#define NRAYS 4096
#define NSTEPS 160
#define NSAMP (NRAYS*NSTEPS)
#define GG 160
#define GG2 (GG*GG)
#define GG3 (GG*GG2)
#define GM 80
#define GM2 (GM*GM)

#define NEARV 0.05f
#define DISTV 0.00625f
#define SVAL 80.0f
#define ACT_SHIFT_C (-9.2102403669758813f)
#define INV2H 40.0f          // 1/(2*VOXEL_SIZE)
#define MASK_THRES_C 1e-3f
#define FAST_THRES_C 1e-7f

// normalized 5-tap gaussian, sigma=1
#define KW0 0.05448868454964295f
#define KW1 0.24420134200323332f
#define KW2 0.40261994689424750f

__device__ __forceinline__ float sigmf(float x){ return 1.0f/(1.0f+__expf(-x)); }
__device__ __forceinline__ float softplusf_(float x){ return (x>20.0f)? x : log1pf(__expf(x)); }

__device__ __forceinline__ void tricoord(float p, int Gx, int& i0, float& fr){
  float u = (p + 1.0f)*0.5f*(float)(Gx-1);
  u = fminf(fmaxf(u, 0.0f), (float)(Gx-1));
  int i = (int)floorf(u);
  i = min(max(i,0), Gx-2);
  i0 = i; fr = u - (float)i;
}

// ---------------- separable gaussian smoothing (zero-pad SAME) ----------------
template<int AXIS>
__global__ __launch_bounds__(256) void ksmooth(const float* __restrict__ in, float* __restrict__ out){
  int idx = blockIdx.x*256 + threadIdx.x;
  if (idx >= GG3) return;
  int c, stride;
  if (AXIS==0){ c = idx / GG2;      stride = GG2; }
  else if (AXIS==1){ c = (idx / GG) % GG; stride = GG; }
  else { c = idx % GG; stride = 1; }
  float acc = KW2*in[idx];
  if (c >= 1)    acc += KW1*in[idx-stride];
  if (c >= 2)    acc += KW0*in[idx-2*stride];
  if (c <= GG-2) acc += KW1*in[idx+stride];
  if (c <= GG-3) acc += KW0*in[idx+2*stride];
  out[idx] = acc;
}

// ---------------- per-sample geometry: mask, sdf+grad trilerp, NeuS alpha ----------------
__global__ __launch_bounds__(256) void kgeom(
  const float* __restrict__ ro, const float* __restrict__ rd,
  const float* __restrict__ vd, const float* __restrict__ maskg,
  const float* __restrict__ sdfs,
  float* __restrict__ grad_out, float* __restrict__ alpha_out)
{
  int idx = blockIdx.x*256 + threadIdx.x;
  if (idx >= NSAMP) return;
  int n = idx / NSTEPS;
  int s = idx - n*NSTEPS;
  float tt = NEARV + DISTV*(float)s;
  float px = ro[n*3+0] + rd[n*3+0]*tt;
  float py = ro[n*3+1] + rd[n*3+1]*tt;
  float pz = ro[n*3+2] + rd[n*3+2]*tt;

  // mask-cache trilerp on 80^3 grid
  int mx,my,mz; float mfx,mfy,mfz;
  tricoord(px, GM, mx, mfx); tricoord(py, GM, my, mfy); tricoord(pz, GM, mz, mfz);
  int mid = (mx*GM + my)*GM + mz;
  float d000=maskg[mid],        d001=maskg[mid+1];
  float d010=maskg[mid+GM],     d011=maskg[mid+GM+1];
  float d100=maskg[mid+GM2],    d101=maskg[mid+GM2+1];
  float d110=maskg[mid+GM2+GM], d111=maskg[mid+GM2+GM+1];
  float m00 = d000 + (d001-d000)*mfz;
  float m01 = d010 + (d011-d010)*mfz;
  float m10 = d100 + (d101-d100)*mfz;
  float m11 = d110 + (d111-d110)*mfz;
  float m0 = m00 + (m01-m00)*mfy;
  float m1 = m10 + (m11-m10)*mfy;
  float dens = m0 + (m1-m0)*mfx;
  float malpha = 1.0f - __expf(-softplusf_(dens + ACT_SHIFT_C)*DISTV);

  // sdf trilerp + on-the-fly central-difference gradient trilerp (160^3)
  int ix,iy,iz; float fx,fy,fz;
  tricoord(px, GG, ix, fx); tricoord(py, GG, iy, fy); tricoord(pz, GG, iz, fz);
  float sdf=0.0f, gx=0.0f, gy=0.0f, gz=0.0f;
  #pragma unroll
  for (int ca=0; ca<2; ca++){
    #pragma unroll
    for (int cb=0; cb<2; cb++){
      #pragma unroll
      for (int cc=0; cc<2; cc++){
        int a=ix+ca, b=iy+cb, c=iz+cc;
        float w = (ca?fx:1.0f-fx)*(cb?fy:1.0f-fy)*(cc?fz:1.0f-fz);
        int id = (a*GG + b)*GG + c;
        sdf += w*sdfs[id];
        if (a>=1 && a<=GG-2) gx += w*INV2H*(sdfs[id+GG2]-sdfs[id-GG2]);
        if (b>=1 && b<=GG-2) gy += w*INV2H*(sdfs[id+GG]-sdfs[id-GG]);
        if (c>=1 && c<=GG-2) gz += w*INV2H*(sdfs[id+1]-sdfs[id-1]);
      }
    }
  }
  float tc = vd[n*3+0]*gx + vd[n*3+1]*gy + vd[n*3+2]*gz;
  float icos = fminf(tc, 0.0f);            // -relu(-true_cos)
  float e = icos*DISTV*0.5f;
  float prev = sigmf((sdf - e)*SVAL);
  float nxt  = sigmf((sdf + e)*SVAL);
  float alpha = (prev - nxt + 1e-5f)/(prev + 1e-5f);
  alpha = fminf(fmaxf(alpha, 0.0f), 1.0f);
  if (!(malpha >= MASK_THRES_C)) alpha = 0.0f;
  alpha_out[idx] = alpha;
  grad_out[idx*3+0]=gx; grad_out[idx*3+1]=gy; grad_out[idx*3+2]=gz;
}

// ---------------- per-ray fused double transmittance scan ----------------
__global__ __launch_bounds__(256) void kscan(
  const float* __restrict__ alpha, float* __restrict__ w2out, float* __restrict__ out)
{
  int n = blockIdx.x*256 + threadIdx.x;
  if (n >= NRAYS) return;
  const float* a = alpha + (size_t)n*NSTEPS;
  float* w2 = w2out + (size_t)n*NSTEPS;
  float T1=1.0f, T2=1.0f, cum=0.0f;
  for (int s=0; s<NSTEPS; s++){
    float av = a[s];
    float w1 = av*T1; T1 *= (1.0f - av);
    float a2 = (w1 > FAST_THRES_C) ? av : 0.0f;
    float wv = a2*T2; T2 *= (1.0f - a2);
    w2[s] = wv; cum += wv;
  }
  out[NRAYS*3 + n] = T2;            // alphainv_last
  out[NRAYS*3 + NRAYS + n] = 1.0f - cum;  // 1 - cum_weights
}

// ---------------- fused feature-build + two MLP heads + blend ----------------
__global__ __launch_bounds__(256) void kmlp(
  const float* __restrict__ ro, const float* __restrict__ rd,
  const float* __restrict__ vd, const int* __restrict__ em,
  const float* __restrict__ offc, const float* __restrict__ emoc,
  const float* __restrict__ grad, const float* __restrict__ w2,
  const float* __restrict__ W0o, const float* __restrict__ b0o,
  const float* __restrict__ W1o, const float* __restrict__ b1o,
  const float* __restrict__ W2o, const float* __restrict__ b2o,
  const float* __restrict__ W0e, const float* __restrict__ b0e,
  const float* __restrict__ W1e, const float* __restrict__ b1e,
  const float* __restrict__ W2e, const float* __restrict__ b2e,
  float* __restrict__ out)
{
  __shared__ float X[16][77];      // [0:3] off color, [3:75] shared features
  __shared__ float EC[16][4];      // emo color
  __shared__ float H[16][129];
  __shared__ float H2[16][129];
  __shared__ float OUTB[16][3];
  __shared__ float WSH[16];
  __shared__ int sflag, smode;

  const int t = threadIdx.x;
  const int base = blockIdx.x * 16;     // 10 blocks per ray, never straddles rays
  const int n = base / NSTEPS;

  if (t < 16) WSH[t] = w2[base + t];
  if (t == 0) smode = em[n];
  __syncthreads();
  if (t == 0) {
    int f = 0;
    #pragma unroll
    for (int s = 0; s < 16; s++) f |= (WSH[s] > 0.0f) ? 1 : 0;
    sflag = f;
  }
  __syncthreads();
  if (!sflag) return;

  // ---- features (16 r-groups x 16 samples) ----
  {
    const int s = t & 15;
    const int r = t >> 4;
    const int samp = base + s;
    const int step = (base % NSTEPS) + s;
    const float tt = NEARV + DISTV*(float)step;
    const float px = ro[n*3+0] + rd[n*3+0]*tt;
    const float py = ro[n*3+1] + rd[n*3+1]*tt;
    const float pz = ro[n*3+2] + rd[n*3+2]*tt;
    if (r < 6) {
      int ix,iy,iz; float fx,fy,fz;
      tricoord(px, GG, ix, fx); tricoord(py, GG, iy, fy); tricoord(pz, GG, iz, fz);
      const int ch = (r < 3) ? r : r-3;
      const float* g = ((r < 3) ? offc : emoc) + (size_t)ch * GG3;
      const int id = (ix*GG + iy)*GG + iz;
      float v000=g[id],        v001=g[id+1];
      float v010=g[id+GG],     v011=g[id+GG+1];
      float v100=g[id+GG2],    v101=g[id+GG2+1];
      float v110=g[id+GG2+GG], v111=g[id+GG2+GG+1];
      float c00 = v000 + (v001-v000)*fz;
      float c01 = v010 + (v011-v010)*fz;
      float c10 = v100 + (v101-v100)*fz;
      float c11 = v110 + (v111-v110)*fz;
      float c0 = c00 + (c01-c00)*fy;
      float c1 = c10 + (c11-c10)*fy;
      float val = c0 + (c1-c0)*fx;
      if (r < 3) X[s][r] = val; else EC[s][ch] = val;
    } else if (r == 6) {
      X[s][3] = (px+1.0f)*0.5f;
      X[s][4] = (py+1.0f)*0.5f;
      X[s][5] = (pz+1.0f)*0.5f;
      float gx = grad[samp*3+0], gy = grad[samp*3+1], gz = grad[samp*3+2];
      float inv = 1.0f/(sqrtf(gx*gx+gy*gy+gz*gz)+1e-5f);
      X[s][72] = gx*inv; X[s][73] = gy*inv; X[s][74] = gz*inv;
    } else if (r < 10) {
      const int a = r - 7;
      const float coord = (a==0)?px:((a==1)?py:pz);
      const float rxyz = (coord+1.0f)*0.5f;
      float fr = 1.0f;
      #pragma unroll
      for (int q = 0; q < 5; q++) {
        float e = rxyz*fr; fr *= 2.0f;
        X[s][6  + a*5 + q] = __sinf(e);
        X[s][21 + a*5 + q] = __cosf(e);
      }
    } else if (r < 13) {
      const int a = r - 10;
      const float v = vd[n*3+a];
      float fr = 1.0f;
      #pragma unroll
      for (int q = 0; q < 4; q++) {
        float e = v*fr; fr *= 2.0f;
        X[s][36 + a*4 + q] = e;
        X[s][48 + a*4 + q] = __sinf(e);
        X[s][60 + a*4 + q] = __cosf(e);
      }
    }
  }
  __syncthreads();

  const int sp = (t & 7) * 2;   // 2 samples per thread
  const int jb = t >> 3;        // 0..31 -> 4 outputs j = jb + 32*i

  // ================= OFF head =================
  {
    float a0[4], a1[4];
    #pragma unroll
    for (int i=0;i<4;i++){ a0[i] = b0o[jb+32*i]; a1[i] = a0[i]; }
    for (int k=0;k<75;k++){
      float x0 = X[sp][k], x1 = X[sp+1][k];
      #pragma unroll
      for (int i=0;i<4;i++){
        float w = W0o[k*128 + jb + 32*i];
        a0[i] += x0*w; a1[i] += x1*w;
      }
    }
    #pragma unroll
    for (int i=0;i<4;i++){
      H[sp][jb+32*i]   = fmaxf(a0[i],0.0f);
      H[sp+1][jb+32*i] = fmaxf(a1[i],0.0f);
    }
  }
  __syncthreads();
  {
    float a0[4], a1[4];
    #pragma unroll
    for (int i=0;i<4;i++){ a0[i] = b1o[jb+32*i]; a1[i] = a0[i]; }
    for (int k=0;k<128;k++){
      float x0 = H[sp][k], x1 = H[sp+1][k];
      #pragma unroll
      for (int i=0;i<4;i++){
        float w = W1o[k*128 + jb + 32*i];
        a0[i] += x0*w; a1[i] += x1*w;
      }
    }
    #pragma unroll
    for (int i=0;i<4;i++){
      H2[sp][jb+32*i]   = fmaxf(a0[i],0.0f);
      H2[sp+1][jb+32*i] = fmaxf(a1[i],0.0f);
    }
  }
  __syncthreads();
  if (t < 48) {
    int s2 = t/3, c = t - s2*3;
    float acc = b2o[c];
    for (int k=0;k<128;k++) acc += H2[s2][k]*W2o[k*3+c];
    OUTB[s2][c] = sigmf(acc);
  }
  __syncthreads();

  // ================= EMO head (only if em_modes[ray]==1) =================
  if (smode) {
    {
      float a0[4], a1[4];
      #pragma unroll
      for (int i=0;i<4;i++){ a0[i] = b0e[jb+32*i]; a1[i] = a0[i]; }
      #pragma unroll
      for (int k=0;k<3;k++){
        float x0 = EC[sp][k], x1 = EC[sp+1][k];
        #pragma unroll
        for (int i=0;i<4;i++){
          float w = W0e[k*128 + jb + 32*i];
          a0[i] += x0*w; a1[i] += x1*w;
        }
      }
      for (int k=3;k<75;k++){
        float x0 = X[sp][k], x1 = X[sp+1][k];
        #pragma unroll
        for (int i=0;i<4;i++){
          float w = W0e[k*128 + jb + 32*i];
          a0[i] += x0*w; a1[i] += x1*w;
        }
      }
      #pragma unroll
      for (int i=0;i<4;i++){
        H[sp][jb+32*i]   = fmaxf(a0[i],0.0f);
        H[sp+1][jb+32*i] = fmaxf(a1[i],0.0f);
      }
    }
    __syncthreads();
    {
      float a0[4], a1[4];
      #pragma unroll
      for (int i=0;i<4;i++){ a0[i] = b1e[jb+32*i]; a1[i] = a0[i]; }
      for (int k=0;k<128;k++){
        float x0 = H[sp][k], x1 = H[sp+1][k];
        #pragma unroll
        for (int i=0;i<4;i++){
          float w = W1e[k*128 + jb + 32*i];
          a0[i] += x0*w; a1[i] += x1*w;
        }
      }
      #pragma unroll
      for (int i=0;i<4;i++){
        H2[sp][jb+32*i]   = fmaxf(a0[i],0.0f);
        H2[sp+1][jb+32*i] = fmaxf(a1[i],0.0f);
      }
    }
    __syncthreads();
    if (t < 48) {
      int s2 = t/3, c = t - s2*3;
      float acc = b2e[c];
      for (int k=0;k<128;k++) acc += H2[s2][k]*W2e[k*3+c];
      OUTB[s2][c] += sigmf(acc);
    }
  }
  __syncthreads();

  if (t < 48) {
    int s2 = t/3, c = t - s2*3;
    float w = WSH[s2];
    if (w > 0.0f) atomicAdd(&out[n*3 + c], w * OUTB[s2][c]);
  }
}

extern "C" void kernel_launch(void* const* d_in, const int* in_sizes, int n_in,
                              void* d_out, int out_size, void* d_ws, size_t ws_size,
                              hipStream_t stream) {
  const float* ro    = (const float*)d_in[0];
  const float* rd    = (const float*)d_in[1];
  const float* vd    = (const float*)d_in[2];
  const int*   em    = (const int*)d_in[3];
  const float* sdfg  = (const float*)d_in[4];
  const float* maskg = (const float*)d_in[5];
  const float* offc  = (const float*)d_in[6];
  const float* emoc  = (const float*)d_in[7];
  const float* W0o = (const float*)d_in[8];
  const float* b0o = (const float*)d_in[9];
  const float* W1o = (const float*)d_in[10];
  const float* b1o = (const float*)d_in[11];
  const float* W2o = (const float*)d_in[12];
  const float* b2o = (const float*)d_in[13];
  const float* W0e = (const float*)d_in[14];
  const float* b0e = (const float*)d_in[15];
  const float* W1e = (const float*)d_in[16];
  const float* b1e = (const float*)d_in[17];
  const float* W2e = (const float*)d_in[18];
  const float* b2e = (const float*)d_in[19];

  float* out = (float*)d_out;
  float* ws  = (float*)d_ws;
  float* bufA  = ws;                 // 160^3
  float* bufB  = ws + GG3;           // 160^3
  float* gradb = ws + 2*GG3;         // NSAMP*3
  float* alphab= gradb + (size_t)NSAMP*3;  // NSAMP
  float* w2b   = alphab + NSAMP;           // NSAMP

  hipMemsetAsync(d_out, 0, (size_t)out_size*sizeof(float), stream);

  ksmooth<0><<<GG3/256, 256, 0, stream>>>(sdfg, bufA);
  ksmooth<1><<<GG3/256, 256, 0, stream>>>(bufA, bufB);
  ksmooth<2><<<GG3/256, 256, 0, stream>>>(bufB, bufA);

  kgeom<<<NSAMP/256, 256, 0, stream>>>(ro, rd, vd, maskg, bufA, gradb, alphab);
  kscan<<<NRAYS/256, 256, 0, stream>>>(alphab, w2b, out);

  kmlp<<<NSAMP/16, 256, 0, stream>>>(ro, rd, vd, em, offc, emoc, gradb, w2b,
                                     W0o,b0o,W1o,b1o,W2o,b2o,
                                     W0e,b0e,W1e,b1e,W2e,b2e, out);
}

// Round 2
// 152.694 us; speedup vs baseline: 3.1516x; 3.1516x over previous
//
#include <hip/hip_runtime.h>

#define NRAYS 4096
#define NSTEPS 160
#define NSAMP (NRAYS*NSTEPS)
#define GG 160
#define GG2 (GG*GG)
#define GG3 (GG*GG2)
#define GM 80
#define GM2 (GM*GM)

#define NEARV 0.05f
#define DISTV 0.00625f
#define SVAL 80.0f
#define ACT_SHIFT_C (-9.2102403669758813f)
#define INV2H 40.0f          // 1/(2*VOXEL_SIZE)
#define MASK_THRES_C 1e-3f
#define FAST_THRES_C 1e-7f

// normalized 5-tap gaussian, sigma=1
#define KW0 0.05448868454964295f
#define KW1 0.24420134200323332f
#define KW2 0.40261994689424750f

__device__ __forceinline__ float sigmf(float x){ return 1.0f/(1.0f+__expf(-x)); }
__device__ __forceinline__ float softplusf_(float x){ return (x>20.0f)? x : log1pf(__expf(x)); }

__device__ __forceinline__ void tricoord(float p, int Gx, int& i0, float& fr){
  float u = (p + 1.0f)*0.5f*(float)(Gx-1);
  u = fminf(fmaxf(u, 0.0f), (float)(Gx-1));
  int i = (int)floorf(u);
  i = min(max(i,0), Gx-2);
  i0 = i; fr = u - (float)i;
}

// ---------------- separable gaussian smoothing (zero-pad SAME) ----------------
template<int AXIS>
__global__ __launch_bounds__(256) void ksmooth(const float* __restrict__ in, float* __restrict__ out){
  int idx = blockIdx.x*256 + threadIdx.x;
  if (idx >= GG3) return;
  int c, stride;
  if (AXIS==0){ c = idx / GG2;      stride = GG2; }
  else if (AXIS==1){ c = (idx / GG) % GG; stride = GG; }
  else { c = idx % GG; stride = 1; }
  float acc = KW2*in[idx];
  if (c >= 1)    acc += KW1*in[idx-stride];
  if (c >= 2)    acc += KW0*in[idx-2*stride];
  if (c <= GG-2) acc += KW1*in[idx+stride];
  if (c <= GG-3) acc += KW0*in[idx+2*stride];
  out[idx] = acc;
}

// ---------------- fused per-ray march: geometry + double scan + compaction ----------------
// Exactness of early break: once T1 <= 1e-7, all later w1 = alpha*T1 <= 1e-7 fail the
// strict (w1 > 1e-7) keep1 test, so alpha2=0, w2=0, T2 and cum frozen.
__global__ __launch_bounds__(64) void kmarch(
  const float* __restrict__ ro, const float* __restrict__ rd,
  const float* __restrict__ vd, const float* __restrict__ maskg,
  const float* __restrict__ sdfs,
  int* __restrict__ slist, float* __restrict__ sw, float* __restrict__ sgrad,
  int* __restrict__ cnt, float* __restrict__ out)
{
  int n = blockIdx.x*64 + threadIdx.x;
  if (n >= NRAYS) return;
  const float ox=ro[n*3+0], oy=ro[n*3+1], oz=ro[n*3+2];
  const float dx=rd[n*3+0], dy=rd[n*3+1], dz=rd[n*3+2];
  const float vx=vd[n*3+0], vy=vd[n*3+1], vz=vd[n*3+2];
  float T1=1.0f, T2=1.0f, cum=0.0f;
  for (int s=0; s<NSTEPS; s++){
    float tt = NEARV + DISTV*(float)s;
    float px = ox + dx*tt, py = oy + dy*tt, pz = oz + dz*tt;

    // mask-cache trilerp on 80^3 grid
    int mx,my,mz; float mfx,mfy,mfz;
    tricoord(px, GM, mx, mfx); tricoord(py, GM, my, mfy); tricoord(pz, GM, mz, mfz);
    int mid = (mx*GM + my)*GM + mz;
    float d000=maskg[mid],        d001=maskg[mid+1];
    float d010=maskg[mid+GM],     d011=maskg[mid+GM+1];
    float d100=maskg[mid+GM2],    d101=maskg[mid+GM2+1];
    float d110=maskg[mid+GM2+GM], d111=maskg[mid+GM2+GM+1];
    float m00 = d000 + (d001-d000)*mfz;
    float m01 = d010 + (d011-d010)*mfz;
    float m10 = d100 + (d101-d100)*mfz;
    float m11 = d110 + (d111-d110)*mfz;
    float m0 = m00 + (m01-m00)*mfy;
    float m1 = m10 + (m11-m10)*mfy;
    float dens = m0 + (m1-m0)*mfx;
    float malpha = 1.0f - __expf(-softplusf_(dens + ACT_SHIFT_C)*DISTV);

    // sdf trilerp + on-the-fly central-difference gradient trilerp (160^3)
    int ix,iy,iz; float fx,fy,fz;
    tricoord(px, GG, ix, fx); tricoord(py, GG, iy, fy); tricoord(pz, GG, iz, fz);
    float sdf=0.0f, gx=0.0f, gy=0.0f, gz=0.0f;
    #pragma unroll
    for (int ca=0; ca<2; ca++){
      #pragma unroll
      for (int cb=0; cb<2; cb++){
        #pragma unroll
        for (int cc=0; cc<2; cc++){
          int a=ix+ca, b=iy+cb, c=iz+cc;
          float w = (ca?fx:1.0f-fx)*(cb?fy:1.0f-fy)*(cc?fz:1.0f-fz);
          int id = (a*GG + b)*GG + c;
          sdf += w*sdfs[id];
          if (a>=1 && a<=GG-2) gx += w*INV2H*(sdfs[id+GG2]-sdfs[id-GG2]);
          if (b>=1 && b<=GG-2) gy += w*INV2H*(sdfs[id+GG]-sdfs[id-GG]);
          if (c>=1 && c<=GG-2) gz += w*INV2H*(sdfs[id+1]-sdfs[id-1]);
        }
      }
    }
    float tc = vx*gx + vy*gy + vz*gz;
    float icos = fminf(tc, 0.0f);
    float e = icos*DISTV*0.5f;
    float prev = sigmf((sdf - e)*SVAL);
    float nxt  = sigmf((sdf + e)*SVAL);
    float alpha = (prev - nxt + 1e-5f)/(prev + 1e-5f);
    alpha = fminf(fmaxf(alpha, 0.0f), 1.0f);
    if (!(malpha >= MASK_THRES_C)) alpha = 0.0f;

    float w1 = alpha*T1; T1 *= (1.0f - alpha);
    float a2 = (w1 > FAST_THRES_C) ? alpha : 0.0f;
    float wv = a2*T2;   T2 *= (1.0f - a2);
    cum += wv;
    if (wv > 0.0f){
      int pos = atomicAdd(cnt, 1);
      slist[pos] = n*NSTEPS + s;
      sw[pos] = wv;
      sgrad[pos*3+0]=gx; sgrad[pos*3+1]=gy; sgrad[pos*3+2]=gz;
    }
    if (T1 <= FAST_THRES_C) break;
  }
  out[NRAYS*3 + n] = T2;
  out[NRAYS*4 + n] = 1.0f - cum;
}

// ---------------- compacted MLP: features + two heads + blend ----------------
__global__ __launch_bounds__(256) void kmlp2(
  const float* __restrict__ ro, const float* __restrict__ rd,
  const float* __restrict__ vd, const int* __restrict__ em,
  const float* __restrict__ offc, const float* __restrict__ emoc,
  const int* __restrict__ slist, const float* __restrict__ sw,
  const float* __restrict__ sgrad, const int* __restrict__ cnt,
  const float* __restrict__ W0o, const float* __restrict__ b0o,
  const float* __restrict__ W1o, const float* __restrict__ b1o,
  const float* __restrict__ W2o, const float* __restrict__ b2o,
  const float* __restrict__ W0e, const float* __restrict__ b0e,
  const float* __restrict__ W1e, const float* __restrict__ b1e,
  const float* __restrict__ W2e, const float* __restrict__ b2e,
  float* __restrict__ out)
{
  __shared__ float X[16][77];      // [0:3] off color, [3:75] shared features
  __shared__ float EC[16][4];      // emo color
  __shared__ float H[16][129];
  __shared__ float H2[16][129];
  __shared__ float PART[16][16][3];
  __shared__ float OUTB[16][3];
  __shared__ float WSH[16];
  __shared__ float GS[16][3];
  __shared__ int SSAMP[16];
  __shared__ int SEM[16];
  __shared__ int s_any_em;

  const int t = threadIdx.x;
  const int count = *cnt;
  const int sp = t & 15;
  const int j8 = t >> 4;

  for (int chunk = blockIdx.x; chunk*16 < count; chunk += gridDim.x) {
    const int base = chunk*16;
    if (t == 0) s_any_em = 0;
    if (t < 16) {
      int i = base + t;
      bool vld = (i < count);
      int samp = vld ? slist[i] : 0;
      SSAMP[t] = samp;
      WSH[t]   = vld ? sw[i] : 0.0f;
      GS[t][0] = vld ? sgrad[i*3+0] : 0.0f;
      GS[t][1] = vld ? sgrad[i*3+1] : 0.0f;
      GS[t][2] = vld ? sgrad[i*3+2] : 1.0f;
      SEM[t]   = vld ? em[samp/NSTEPS] : 0;
    }
    __syncthreads();
    if (t < 16 && SEM[t] != 0 && WSH[t] > 0.0f) s_any_em = 1;

    // ---- features (13 r-groups x 16 samples) ----
    {
      const int s = t & 15;
      const int r = t >> 4;
      const int samp = SSAMP[s];
      const int n = samp / NSTEPS;
      const int step = samp - n*NSTEPS;
      const float tt = NEARV + DISTV*(float)step;
      const float px = ro[n*3+0] + rd[n*3+0]*tt;
      const float py = ro[n*3+1] + rd[n*3+1]*tt;
      const float pz = ro[n*3+2] + rd[n*3+2]*tt;
      if (r < 6) {
        int ix,iy,iz; float fx,fy,fz;
        tricoord(px, GG, ix, fx); tricoord(py, GG, iy, fy); tricoord(pz, GG, iz, fz);
        const int ch = (r < 3) ? r : r-3;
        const float* g = ((r < 3) ? offc : emoc) + (size_t)ch * GG3;
        const int id = (ix*GG + iy)*GG + iz;
        float v000=g[id],        v001=g[id+1];
        float v010=g[id+GG],     v011=g[id+GG+1];
        float v100=g[id+GG2],    v101=g[id+GG2+1];
        float v110=g[id+GG2+GG], v111=g[id+GG2+GG+1];
        float c00 = v000 + (v001-v000)*fz;
        float c01 = v010 + (v011-v010)*fz;
        float c10 = v100 + (v101-v100)*fz;
        float c11 = v110 + (v111-v110)*fz;
        float c0 = c00 + (c01-c00)*fy;
        float c1 = c10 + (c11-c10)*fy;
        float val = c0 + (c1-c0)*fx;
        if (r < 3) X[s][r] = val; else EC[s][ch] = val;
      } else if (r == 6) {
        X[s][3] = (px+1.0f)*0.5f;
        X[s][4] = (py+1.0f)*0.5f;
        X[s][5] = (pz+1.0f)*0.5f;
        float gx = GS[s][0], gy = GS[s][1], gz = GS[s][2];
        float inv = 1.0f/(sqrtf(gx*gx+gy*gy+gz*gz)+1e-5f);
        X[s][72] = gx*inv; X[s][73] = gy*inv; X[s][74] = gz*inv;
      } else if (r < 10) {
        const int a = r - 7;
        const float coord = (a==0)?px:((a==1)?py:pz);
        const float rxyz = (coord+1.0f)*0.5f;
        float fr = 1.0f;
        #pragma unroll
        for (int q = 0; q < 5; q++) {
          float e = rxyz*fr; fr *= 2.0f;
          X[s][6  + a*5 + q] = __sinf(e);
          X[s][21 + a*5 + q] = __cosf(e);
        }
      } else if (r < 13) {
        const int a = r - 10;
        const float v = vd[n*3+a];
        float fr = 1.0f;
        #pragma unroll
        for (int q = 0; q < 4; q++) {
          float e = v*fr; fr *= 2.0f;
          X[s][36 + a*4 + q] = e;
          X[s][48 + a*4 + q] = __sinf(e);
          X[s][60 + a*4 + q] = __cosf(e);
        }
      }
    }
    __syncthreads();

    // ================= OFF head =================
    {
      float acc[8];
      #pragma unroll
      for (int i=0;i<8;i++) acc[i] = b0o[j8*8+i];
      const float4* W4 = (const float4*)W0o;
      #pragma unroll 5
      for (int k=0;k<75;k++){
        float x = X[sp][k];
        float4 wa = W4[k*32 + j8*2];
        float4 wb = W4[k*32 + j8*2 + 1];
        acc[0]+=x*wa.x; acc[1]+=x*wa.y; acc[2]+=x*wa.z; acc[3]+=x*wa.w;
        acc[4]+=x*wb.x; acc[5]+=x*wb.y; acc[6]+=x*wb.z; acc[7]+=x*wb.w;
      }
      #pragma unroll
      for (int i=0;i<8;i++) H[sp][j8*8+i] = fmaxf(acc[i],0.0f);
    }
    __syncthreads();
    {
      float acc[8];
      #pragma unroll
      for (int i=0;i<8;i++) acc[i] = b1o[j8*8+i];
      const float4* W4 = (const float4*)W1o;
      #pragma unroll 4
      for (int k=0;k<128;k++){
        float x = H[sp][k];
        float4 wa = W4[k*32 + j8*2];
        float4 wb = W4[k*32 + j8*2 + 1];
        acc[0]+=x*wa.x; acc[1]+=x*wa.y; acc[2]+=x*wa.z; acc[3]+=x*wa.w;
        acc[4]+=x*wb.x; acc[5]+=x*wb.y; acc[6]+=x*wb.z; acc[7]+=x*wb.w;
      }
      #pragma unroll
      for (int i=0;i<8;i++) H2[sp][j8*8+i] = fmaxf(acc[i],0.0f);
    }
    __syncthreads();
    {
      float a0=0.0f,a1=0.0f,a2v=0.0f;
      #pragma unroll
      for (int kk=0;kk<8;kk++){
        float h = H2[sp][j8*8+kk];
        a0  += h*W2o[(j8*8+kk)*3+0];
        a1  += h*W2o[(j8*8+kk)*3+1];
        a2v += h*W2o[(j8*8+kk)*3+2];
      }
      PART[sp][j8][0]=a0; PART[sp][j8][1]=a1; PART[sp][j8][2]=a2v;
    }
    __syncthreads();
    if (t < 48) {
      int s2 = t/3, c = t - s2*3;
      float acc = b2o[c];
      #pragma unroll
      for (int g=0; g<16; g++) acc += PART[s2][g][c];
      OUTB[s2][c] = sigmf(acc);
    }
    __syncthreads();

    // ================= EMO head (if any sample's ray has em==1) =================
    if (s_any_em) {
      {
        float acc[8];
        #pragma unroll
        for (int i=0;i<8;i++) acc[i] = b0e[j8*8+i];
        const float4* W4 = (const float4*)W0e;
        #pragma unroll
        for (int k=0;k<3;k++){
          float x = EC[sp][k];
          float4 wa = W4[k*32 + j8*2];
          float4 wb = W4[k*32 + j8*2 + 1];
          acc[0]+=x*wa.x; acc[1]+=x*wa.y; acc[2]+=x*wa.z; acc[3]+=x*wa.w;
          acc[4]+=x*wb.x; acc[5]+=x*wb.y; acc[6]+=x*wb.z; acc[7]+=x*wb.w;
        }
        #pragma unroll 4
        for (int k=3;k<75;k++){
          float x = X[sp][k];
          float4 wa = W4[k*32 + j8*2];
          float4 wb = W4[k*32 + j8*2 + 1];
          acc[0]+=x*wa.x; acc[1]+=x*wa.y; acc[2]+=x*wa.z; acc[3]+=x*wa.w;
          acc[4]+=x*wb.x; acc[5]+=x*wb.y; acc[6]+=x*wb.z; acc[7]+=x*wb.w;
        }
        #pragma unroll
        for (int i=0;i<8;i++) H[sp][j8*8+i] = fmaxf(acc[i],0.0f);
      }
      __syncthreads();
      {
        float acc[8];
        #pragma unroll
        for (int i=0;i<8;i++) acc[i] = b1e[j8*8+i];
        const float4* W4 = (const float4*)W1e;
        #pragma unroll 4
        for (int k=0;k<128;k++){
          float x = H[sp][k];
          float4 wa = W4[k*32 + j8*2];
          float4 wb = W4[k*32 + j8*2 + 1];
          acc[0]+=x*wa.x; acc[1]+=x*wa.y; acc[2]+=x*wa.z; acc[3]+=x*wa.w;
          acc[4]+=x*wb.x; acc[5]+=x*wb.y; acc[6]+=x*wb.z; acc[7]+=x*wb.w;
        }
        #pragma unroll
        for (int i=0;i<8;i++) H2[sp][j8*8+i] = fmaxf(acc[i],0.0f);
      }
      __syncthreads();
      {
        float a0=0.0f,a1=0.0f,a2v=0.0f;
        #pragma unroll
        for (int kk=0;kk<8;kk++){
          float h = H2[sp][j8*8+kk];
          a0  += h*W2e[(j8*8+kk)*3+0];
          a1  += h*W2e[(j8*8+kk)*3+1];
          a2v += h*W2e[(j8*8+kk)*3+2];
        }
        PART[sp][j8][0]=a0; PART[sp][j8][1]=a1; PART[sp][j8][2]=a2v;
      }
      __syncthreads();
      if (t < 48) {
        int s2 = t/3, c = t - s2*3;
        if (SEM[s2]) {
          float acc = b2e[c];
          #pragma unroll
          for (int g=0; g<16; g++) acc += PART[s2][g][c];
          OUTB[s2][c] += sigmf(acc);
        }
      }
      __syncthreads();
    }

    if (t < 48) {
      int s2 = t/3, c = t - s2*3;
      float w = WSH[s2];
      if (w > 0.0f) {
        int n2 = SSAMP[s2]/NSTEPS;
        atomicAdd(&out[n2*3 + c], w * OUTB[s2][c]);
      }
    }
    __syncthreads();
  }
}

extern "C" void kernel_launch(void* const* d_in, const int* in_sizes, int n_in,
                              void* d_out, int out_size, void* d_ws, size_t ws_size,
                              hipStream_t stream) {
  const float* ro    = (const float*)d_in[0];
  const float* rd    = (const float*)d_in[1];
  const float* vd    = (const float*)d_in[2];
  const int*   em    = (const int*)d_in[3];
  const float* sdfg  = (const float*)d_in[4];
  const float* maskg = (const float*)d_in[5];
  const float* offc  = (const float*)d_in[6];
  const float* emoc  = (const float*)d_in[7];
  const float* W0o = (const float*)d_in[8];
  const float* b0o = (const float*)d_in[9];
  const float* W1o = (const float*)d_in[10];
  const float* b1o = (const float*)d_in[11];
  const float* W2o = (const float*)d_in[12];
  const float* b2o = (const float*)d_in[13];
  const float* W0e = (const float*)d_in[14];
  const float* b0e = (const float*)d_in[15];
  const float* W1e = (const float*)d_in[16];
  const float* b1e = (const float*)d_in[17];
  const float* W2e = (const float*)d_in[18];
  const float* b2e = (const float*)d_in[19];

  float* out = (float*)d_out;
  float* ws  = (float*)d_ws;
  float* bufA  = ws;                         // GG3
  float* bufB  = ws + GG3;                   // GG3
  float* swb   = ws + 2*GG3;                 // NSAMP
  float* sgradb= swb + NSAMP;                // 3*NSAMP
  int*   slist = (int*)(sgradb + 3*(size_t)NSAMP);  // NSAMP
  int*   cnt   = slist + NSAMP;              // 1

  hipMemsetAsync(d_out, 0, (size_t)out_size*sizeof(float), stream);
  hipMemsetAsync(cnt, 0, sizeof(int), stream);

  ksmooth<0><<<GG3/256, 256, 0, stream>>>(sdfg, bufA);
  ksmooth<1><<<GG3/256, 256, 0, stream>>>(bufA, bufB);
  ksmooth<2><<<GG3/256, 256, 0, stream>>>(bufB, bufA);

  kmarch<<<NRAYS/64, 64, 0, stream>>>(ro, rd, vd, maskg, bufA,
                                      slist, swb, sgradb, cnt, out);

  kmlp2<<<1024, 256, 0, stream>>>(ro, rd, vd, em, offc, emoc,
                                  slist, swb, sgradb, cnt,
                                  W0o,b0o,W1o,b1o,W2o,b2o,
                                  W0e,b0e,W1e,b1e,W2e,b2e, out);
}

// Round 3
// 85.184 us; speedup vs baseline: 5.6493x; 1.7925x over previous
//
#include <hip/hip_runtime.h>

#define NRAYS 4096
#define NSTEPS 160
#define NSAMP (NRAYS*NSTEPS)
#define GG 160
#define GG2 (GG*GG)
#define GG3 (GG*GG2)
#define GM 80
#define GM2 (GM*GM)

#define NEARV 0.05f
#define DISTV 0.00625f
#define SVAL 80.0f
#define ACT_SHIFT_C (-9.2102403669758813f)
#define INV2H 40.0f          // 1/(2*VOXEL_SIZE)
#define MASK_THRES_C 1e-3f
#define FAST_THRES_C 1e-7f

// normalized 5-tap gaussian, sigma=1
#define KW0 0.05448868454964295f
#define KW1 0.24420134200323332f
#define KW2 0.40261994689424750f

__device__ __forceinline__ float sigmf(float x){ return 1.0f/(1.0f+__expf(-x)); }
__device__ __forceinline__ float softplusf_(float x){ return (x>20.0f)? x : log1pf(__expf(x)); }

__device__ __forceinline__ void tricoord(float p, int Gx, int& i0, float& fr){
  float u = (p + 1.0f)*0.5f*(float)(Gx-1);
  u = fminf(fmaxf(u, 0.0f), (float)(Gx-1));
  int i = (int)floorf(u);
  i = min(max(i,0), Gx-2);
  i0 = i; fr = u - (float)i;
}

// ---------------- fused y+z gaussian passes (zero-pad SAME), LDS tiled ----------------
__global__ __launch_bounds__(256) void ksmooth_yz(const float* __restrict__ in, float* __restrict__ out){
  __shared__ float S[36][37];
  __shared__ float Tz[36][33];
  const int bx = blockIdx.x;          // 160 * 25
  const int x  = bx / 25;
  const int tile = bx % 25;
  const int Y0 = (tile/5)*32, Z0 = (tile%5)*32;
  const int t = threadIdx.x;
  const float kw[5] = {KW0,KW1,KW2,KW1,KW0};
  for (int i = t; i < 36*36; i += 256){
    int r = i/36, c = i - (i/36)*36;
    int y = Y0 + r - 2, z = Z0 + c - 2;
    float v = 0.0f;
    if (y>=0 && y<GG && z>=0 && z<GG) v = in[(x*GG+y)*GG+z];
    S[r][c] = v;
  }
  __syncthreads();
  for (int i = t; i < 36*32; i += 256){
    int r = i >> 5, c = i & 31;
    float acc = 0.f;
    #pragma unroll
    for (int d=0; d<5; d++) acc += kw[d]*S[r][c+d];
    Tz[r][c] = acc;
  }
  __syncthreads();
  for (int i = t; i < 32*32; i += 256){
    int yy = i >> 5, c = i & 31;
    float acc = 0.f;
    #pragma unroll
    for (int d=0; d<5; d++) acc += kw[d]*Tz[yy+d][c];
    out[(x*GG + Y0+yy)*GG + Z0 + c] = acc;
  }
}

// ---------------- x-axis gaussian pass ----------------
__global__ __launch_bounds__(256) void ksmooth_x(const float* __restrict__ in, float* __restrict__ out){
  int idx = blockIdx.x*256 + threadIdx.x;
  if (idx >= GG3) return;
  int c = idx / GG2;
  float acc = KW2*in[idx];
  if (c >= 1)    acc += KW1*in[idx-GG2];
  if (c >= 2)    acc += KW0*in[idx-2*GG2];
  if (c <= GG-2) acc += KW1*in[idx+GG2];
  if (c <= GG-3) acc += KW0*in[idx+2*GG2];
  out[idx] = acc;
}

// ---------------- fused per-ray march: geometry + double scan + compaction ----------------
// Early break exact: once T1 <= 1e-7, all later w1 = alpha*T1 <= 1e-7 fail strict > test.
__global__ __launch_bounds__(64) void kmarch(
  const float* __restrict__ ro, const float* __restrict__ rd,
  const float* __restrict__ vd, const float* __restrict__ maskg,
  const float* __restrict__ sdfs,
  int* __restrict__ slist, float* __restrict__ sw, float* __restrict__ sgrad,
  int* __restrict__ cnt, float* __restrict__ out)
{
  int n = blockIdx.x*64 + threadIdx.x;
  if (n >= NRAYS) return;
  const float ox=ro[n*3+0], oy=ro[n*3+1], oz=ro[n*3+2];
  const float dx=rd[n*3+0], dy=rd[n*3+1], dz=rd[n*3+2];
  const float vx=vd[n*3+0], vy=vd[n*3+1], vz=vd[n*3+2];
  float T1=1.0f, T2=1.0f, cum=0.0f;
  for (int s=0; s<NSTEPS; s++){
    float tt = NEARV + DISTV*(float)s;
    float px = ox + dx*tt, py = oy + dy*tt, pz = oz + dz*tt;

    int mx,my,mz; float mfx,mfy,mfz;
    tricoord(px, GM, mx, mfx); tricoord(py, GM, my, mfy); tricoord(pz, GM, mz, mfz);
    int mid = (mx*GM + my)*GM + mz;
    float d000=maskg[mid],        d001=maskg[mid+1];
    float d010=maskg[mid+GM],     d011=maskg[mid+GM+1];
    float d100=maskg[mid+GM2],    d101=maskg[mid+GM2+1];
    float d110=maskg[mid+GM2+GM], d111=maskg[mid+GM2+GM+1];
    float m00 = d000 + (d001-d000)*mfz;
    float m01 = d010 + (d011-d010)*mfz;
    float m10 = d100 + (d101-d100)*mfz;
    float m11 = d110 + (d111-d110)*mfz;
    float m0 = m00 + (m01-m00)*mfy;
    float m1 = m10 + (m11-m10)*mfy;
    float dens = m0 + (m1-m0)*mfx;
    float malpha = 1.0f - __expf(-softplusf_(dens + ACT_SHIFT_C)*DISTV);

    int ix,iy,iz; float fx,fy,fz;
    tricoord(px, GG, ix, fx); tricoord(py, GG, iy, fy); tricoord(pz, GG, iz, fz);
    float sdf=0.0f, gx=0.0f, gy=0.0f, gz=0.0f;
    #pragma unroll
    for (int ca=0; ca<2; ca++){
      #pragma unroll
      for (int cb=0; cb<2; cb++){
        #pragma unroll
        for (int cc=0; cc<2; cc++){
          int a=ix+ca, b=iy+cb, c=iz+cc;
          float w = (ca?fx:1.0f-fx)*(cb?fy:1.0f-fy)*(cc?fz:1.0f-fz);
          int id = (a*GG + b)*GG + c;
          sdf += w*sdfs[id];
          if (a>=1 && a<=GG-2) gx += w*INV2H*(sdfs[id+GG2]-sdfs[id-GG2]);
          if (b>=1 && b<=GG-2) gy += w*INV2H*(sdfs[id+GG]-sdfs[id-GG]);
          if (c>=1 && c<=GG-2) gz += w*INV2H*(sdfs[id+1]-sdfs[id-1]);
        }
      }
    }
    float tc = vx*gx + vy*gy + vz*gz;
    float icos = fminf(tc, 0.0f);
    float e = icos*DISTV*0.5f;
    float prev = sigmf((sdf - e)*SVAL);
    float nxt  = sigmf((sdf + e)*SVAL);
    float alpha = (prev - nxt + 1e-5f)/(prev + 1e-5f);
    alpha = fminf(fmaxf(alpha, 0.0f), 1.0f);
    if (!(malpha >= MASK_THRES_C)) alpha = 0.0f;

    float w1 = alpha*T1; T1 *= (1.0f - alpha);
    float a2 = (w1 > FAST_THRES_C) ? alpha : 0.0f;
    float wv = a2*T2;   T2 *= (1.0f - a2);
    cum += wv;
    if (wv > 0.0f){
      int pos = atomicAdd(cnt, 1);
      slist[pos] = n*NSTEPS + s;
      sw[pos] = wv;
      sgrad[pos*3+0]=gx; sgrad[pos*3+1]=gy; sgrad[pos*3+2]=gz;
    }
    if (T1 <= FAST_THRES_C) break;
  }
  out[NRAYS*3 + n] = T2;
  out[NRAYS*4 + n] = 1.0f - cum;
}

// ---------------- compacted MLP: one head per block, 8 samples, 32 thr/sample ----------------
__global__ __launch_bounds__(256) void kmlp3(
  const float* __restrict__ ro, const float* __restrict__ rd,
  const float* __restrict__ vd, const int* __restrict__ em,
  const float* __restrict__ offc, const float* __restrict__ emoc,
  const int* __restrict__ slist, const float* __restrict__ sw,
  const float* __restrict__ sgrad, const int* __restrict__ cnt,
  const float* __restrict__ W0o, const float* __restrict__ b0o,
  const float* __restrict__ W1o, const float* __restrict__ b1o,
  const float* __restrict__ W2o, const float* __restrict__ b2o,
  const float* __restrict__ W0e, const float* __restrict__ b0e,
  const float* __restrict__ W1e, const float* __restrict__ b1e,
  const float* __restrict__ W2e, const float* __restrict__ b2e,
  float* __restrict__ out)
{
  __shared__ float X[8][80];
  __shared__ float H[8][132];
  __shared__ float H2[8][132];
  __shared__ float OUTB[8][3];
  __shared__ float WSH[8];
  __shared__ float GS[8][3];
  __shared__ int SSAMP[8];
  __shared__ int SEM[8];
  __shared__ int s_go;

  const int t = threadIdx.x;
  const int count = *cnt;
  const int head = blockIdx.x & 1;
  const int cstride = gridDim.x >> 1;

  const float* W0 = head ? W0e : W0o;  const float* b0 = head ? b0e : b0o;
  const float* W1 = head ? W1e : W1o;  const float* b1 = head ? b1e : b1o;
  const float* W2 = head ? W2e : W2o;  const float* b2 = head ? b2e : b2o;
  const float* cg = head ? emoc : offc;
  const float4* W04 = (const float4*)W0;
  const float4* W14 = (const float4*)W1;

  const int sp   = t >> 5;     // sample 0..7
  const int lane = t & 31;     // 32 threads per sample, 4 outputs each

  for (int chunk = blockIdx.x >> 1; chunk*8 < count; chunk += cstride) {
    const int base = chunk*8;
    if (t == 0) s_go = 0;
    if (t < 8) {
      int i = base + t;
      bool vld = (i < count);
      int samp = vld ? slist[i] : 0;
      SSAMP[t] = samp;
      WSH[t]   = vld ? sw[i] : 0.0f;
      GS[t][0] = vld ? sgrad[i*3+0] : 0.0f;
      GS[t][1] = vld ? sgrad[i*3+1] : 0.0f;
      GS[t][2] = vld ? sgrad[i*3+2] : 0.0f;
      SEM[t]   = vld ? em[samp/NSTEPS] : 0;
    }
    __syncthreads();
    if (t < 8) {
      bool live = (WSH[t] > 0.0f) && (head == 0 || SEM[t] != 0);
      if (live) s_go = 1;
    }
    __syncthreads();

    if (s_go) {
      // ---- features: s = t&7 sample, r = t>>3 group (0..31, 10 used) ----
      {
        const int s = t & 7;
        const int r = t >> 3;
        const int samp = SSAMP[s];
        const int n = samp / NSTEPS;
        const int step = samp - n*NSTEPS;
        const float tt = NEARV + DISTV*(float)step;
        const float px = ro[n*3+0] + rd[n*3+0]*tt;
        const float py = ro[n*3+1] + rd[n*3+1]*tt;
        const float pz = ro[n*3+2] + rd[n*3+2]*tt;
        if (r < 3) {
          int ix,iy,iz; float fx,fy,fz;
          tricoord(px, GG, ix, fx); tricoord(py, GG, iy, fy); tricoord(pz, GG, iz, fz);
          const float* g = cg + (size_t)r * GG3;
          const int id = (ix*GG + iy)*GG + iz;
          float v000=g[id],        v001=g[id+1];
          float v010=g[id+GG],     v011=g[id+GG+1];
          float v100=g[id+GG2],    v101=g[id+GG2+1];
          float v110=g[id+GG2+GG], v111=g[id+GG2+GG+1];
          float c00 = v000 + (v001-v000)*fz;
          float c01 = v010 + (v011-v010)*fz;
          float c10 = v100 + (v101-v100)*fz;
          float c11 = v110 + (v111-v110)*fz;
          float c0 = c00 + (c01-c00)*fy;
          float c1 = c10 + (c11-c10)*fy;
          X[s][r] = c0 + (c1-c0)*fx;
        } else if (r == 3) {
          X[s][3] = (px+1.0f)*0.5f;
          X[s][4] = (py+1.0f)*0.5f;
          X[s][5] = (pz+1.0f)*0.5f;
          float gx = GS[s][0], gy = GS[s][1], gz = GS[s][2];
          float inv = 1.0f/(sqrtf(gx*gx+gy*gy+gz*gz)+1e-5f);
          X[s][72] = gx*inv; X[s][73] = gy*inv; X[s][74] = gz*inv;
        } else if (r < 7) {
          const int a = r - 4;
          const float coord = (a==0)?px:((a==1)?py:pz);
          const float rxyz = (coord+1.0f)*0.5f;
          float fr = 1.0f;
          #pragma unroll
          for (int q = 0; q < 5; q++) {
            float e = rxyz*fr; fr *= 2.0f;
            X[s][6  + a*5 + q] = __sinf(e);
            X[s][21 + a*5 + q] = __cosf(e);
          }
        } else if (r < 10) {
          const int a = r - 7;
          const float v = vd[n*3+a];
          float fr = 1.0f;
          #pragma unroll
          for (int q = 0; q < 4; q++) {
            float e = v*fr; fr *= 2.0f;
            X[s][36 + a*4 + q] = e;
            X[s][48 + a*4 + q] = __sinf(e);
            X[s][60 + a*4 + q] = __cosf(e);
          }
        }
      }
      __syncthreads();

      // ---- layer 0: 75 -> 128 ----
      {
        float4 acc = ((const float4*)b0)[lane];
        #pragma unroll 5
        for (int k=0; k<75; k++){
          float x = X[sp][k];
          float4 w = W04[k*32 + lane];
          acc.x += x*w.x; acc.y += x*w.y; acc.z += x*w.z; acc.w += x*w.w;
        }
        H[sp][lane*4+0] = fmaxf(acc.x,0.0f);
        H[sp][lane*4+1] = fmaxf(acc.y,0.0f);
        H[sp][lane*4+2] = fmaxf(acc.z,0.0f);
        H[sp][lane*4+3] = fmaxf(acc.w,0.0f);
      }
      __syncthreads();

      // ---- layer 1: 128 -> 128 ----
      {
        float4 acc = ((const float4*)b1)[lane];
        #pragma unroll 8
        for (int k=0; k<128; k++){
          float x = H[sp][k];
          float4 w = W14[k*32 + lane];
          acc.x += x*w.x; acc.y += x*w.y; acc.z += x*w.z; acc.w += x*w.w;
        }
        H2[sp][lane*4+0] = fmaxf(acc.x,0.0f);
        H2[sp][lane*4+1] = fmaxf(acc.y,0.0f);
        H2[sp][lane*4+2] = fmaxf(acc.z,0.0f);
        H2[sp][lane*4+3] = fmaxf(acc.w,0.0f);
      }
      __syncthreads();

      // ---- layer 2: 128 -> 3, 32-lane shuffle reduce ----
      {
        float a0=0.0f, a1=0.0f, a2v=0.0f;
        #pragma unroll
        for (int i=0;i<4;i++){
          int k = lane*4+i;
          float h = H2[sp][k];
          a0  += h*W2[k*3+0];
          a1  += h*W2[k*3+1];
          a2v += h*W2[k*3+2];
        }
        #pragma unroll
        for (int d=16; d>=1; d>>=1){
          a0  += __shfl_down(a0,  d, 32);
          a1  += __shfl_down(a1,  d, 32);
          a2v += __shfl_down(a2v, d, 32);
        }
        if (lane == 0){
          OUTB[sp][0] = sigmf(a0  + b2[0]);
          OUTB[sp][1] = sigmf(a1  + b2[1]);
          OUTB[sp][2] = sigmf(a2v + b2[2]);
        }
      }
      __syncthreads();

      if (t < 24) {
        int s2 = t/3, c = t - s2*3;
        float w = WSH[s2];
        if (w > 0.0f && (head == 0 || SEM[s2] != 0)) {
          int n2 = SSAMP[s2]/NSTEPS;
          atomicAdd(&out[n2*3 + c], w * OUTB[s2][c]);
        }
      }
    }
    __syncthreads();
  }
}

extern "C" void kernel_launch(void* const* d_in, const int* in_sizes, int n_in,
                              void* d_out, int out_size, void* d_ws, size_t ws_size,
                              hipStream_t stream) {
  const float* ro    = (const float*)d_in[0];
  const float* rd    = (const float*)d_in[1];
  const float* vd    = (const float*)d_in[2];
  const int*   em    = (const int*)d_in[3];
  const float* sdfg  = (const float*)d_in[4];
  const float* maskg = (const float*)d_in[5];
  const float* offc  = (const float*)d_in[6];
  const float* emoc  = (const float*)d_in[7];
  const float* W0o = (const float*)d_in[8];
  const float* b0o = (const float*)d_in[9];
  const float* W1o = (const float*)d_in[10];
  const float* b1o = (const float*)d_in[11];
  const float* W2o = (const float*)d_in[12];
  const float* b2o = (const float*)d_in[13];
  const float* W0e = (const float*)d_in[14];
  const float* b0e = (const float*)d_in[15];
  const float* W1e = (const float*)d_in[16];
  const float* b1e = (const float*)d_in[17];
  const float* W2e = (const float*)d_in[18];
  const float* b2e = (const float*)d_in[19];

  float* out = (float*)d_out;
  float* ws  = (float*)d_ws;
  float* bufA  = ws;                         // GG3
  float* bufB  = ws + GG3;                   // GG3
  float* swb   = ws + 2*GG3;                 // NSAMP
  float* sgradb= swb + NSAMP;                // 3*NSAMP
  int*   slist = (int*)(sgradb + 3*(size_t)NSAMP);  // NSAMP
  int*   cnt   = slist + NSAMP;              // 1

  hipMemsetAsync(d_out, 0, (size_t)out_size*sizeof(float), stream);
  hipMemsetAsync(cnt, 0, sizeof(int), stream);

  ksmooth_yz<<<GG*25, 256, 0, stream>>>(sdfg, bufB);
  ksmooth_x<<<GG3/256, 256, 0, stream>>>(bufB, bufA);

  kmarch<<<NRAYS/64, 64, 0, stream>>>(ro, rd, vd, maskg, bufA,
                                      slist, swb, sgradb, cnt, out);

  kmlp3<<<2048, 256, 0, stream>>>(ro, rd, vd, em, offc, emoc,
                                  slist, swb, sgradb, cnt,
                                  W0o,b0o,W1o,b1o,W2o,b2o,
                                  W0e,b0e,W1e,b1e,W2e,b2e, out);
}